// Round 1
// baseline (427.574 us; speedup 1.0000x reference)
//
#include <hip/hip_runtime.h>
#include <hip/hip_bf16.h>

// MHA: B=4, S=2048, D=1024, H=16, HD=64. fp32 in/out, bf16 MFMA internally.
typedef __bf16 bf16;
typedef __bf16 bf16x8 __attribute__((ext_vector_type(8)));
typedef __bf16 bf16x4 __attribute__((ext_vector_type(4)));
typedef float f32x4 __attribute__((ext_vector_type(4)));

#define B_ 4
#define S_ 2048
#define D_ 1024
#define H_ 16
#define HD_ 64

static __device__ __forceinline__ f32x4 mfma16(bf16x8 a, bf16x8 b, f32x4 c) {
  return __builtin_amdgcn_mfma_f32_16x16x32_bf16(a, b, c, 0, 0, 0);
}

static __device__ __forceinline__ void gload_lds16(const void* g, void* l) {
  __builtin_amdgcn_global_load_lds(
      (const __attribute__((address_space(1))) void*)g,
      (__attribute__((address_space(3))) void*)l, 16, 0, 0);
}

// ---------------- fp32 -> bf16 conversion ----------------
__global__ void cvt_kernel(const float* __restrict__ in, bf16* __restrict__ out, int n4) {
  int i = blockIdx.x * blockDim.x + threadIdx.x;
  const int stride = gridDim.x * blockDim.x;
  for (; i < n4; i += stride) {
    float4 v = reinterpret_cast<const float4*>(in)[i];
    bf16x4 o;
    o[0] = (bf16)v.x; o[1] = (bf16)v.y; o[2] = (bf16)v.z; o[3] = (bf16)v.w;
    reinterpret_cast<bf16x4*>(out)[i] = o;
  }
}

// ---------------- GEMM: C[m][n] = sum_k A[m][k]*W[n][k] + bias[n] ----------------
// 128x128 tile, BK=32, 4 waves (2x2), each wave 64x64 output.
template<bool OUT_BF16>
__global__ __launch_bounds__(256)
void gemm_bt(const bf16* __restrict__ A, const bf16* __restrict__ W,
             const float* __restrict__ bias, void* __restrict__ Cout,
             int M, int N, int K) {
  __shared__ bf16 Alds[128 * 32];
  __shared__ bf16 Blds[128 * 32];
  const int tid = threadIdx.x;
  const int wave = tid >> 6, lane = tid & 63;
  const int g = lane >> 4, r16 = lane & 15;
  const int m0 = blockIdx.y * 128, n0 = blockIdx.x * 128;
  const int wm = (wave >> 1) * 64, wn = (wave & 1) * 64;

  f32x4 acc[4][4] = {};

  // staging: wave w covers rows [w*32, w*32+32), two 1KB global_load_lds calls
  const int srow = (wave << 5) + (lane >> 2);
  const int scol = (lane & 3) << 3;
  const int nkt = K >> 5;

  for (int kt = 0; kt < nkt; ++kt) {
    __syncthreads();
    const int kb = kt << 5;
    gload_lds16(&A[(size_t)(m0 + srow) * K + kb + scol],      &Alds[(wave << 10)]);
    gload_lds16(&A[(size_t)(m0 + srow + 16) * K + kb + scol], &Alds[(wave << 10) + 512]);
    gload_lds16(&W[(size_t)(n0 + srow) * K + kb + scol],      &Blds[(wave << 10)]);
    gload_lds16(&W[(size_t)(n0 + srow + 16) * K + kb + scol], &Blds[(wave << 10) + 512]);
    __syncthreads();

    bf16x8 af[4], bf_[4];
#pragma unroll
    for (int i = 0; i < 4; ++i) {
      af[i]  = *reinterpret_cast<const bf16x8*>(&Alds[(wm + i * 16 + r16) * 32 + g * 8]);
      bf_[i] = *reinterpret_cast<const bf16x8*>(&Blds[(wn + i * 16 + r16) * 32 + g * 8]);
    }
#pragma unroll
    for (int i = 0; i < 4; ++i)
#pragma unroll
      for (int j = 0; j < 4; ++j)
        acc[i][j] = mfma16(af[i], bf_[j], acc[i][j]);
  }

#pragma unroll
  for (int i = 0; i < 4; ++i) {
#pragma unroll
    for (int j = 0; j < 4; ++j) {
      const int col = n0 + wn + j * 16 + r16;
      const float bv = bias[col];
#pragma unroll
      for (int r = 0; r < 4; ++r) {
        const int row = m0 + wm + i * 16 + g * 4 + r;
        const float v = acc[i][j][r] + bv;
        if (OUT_BF16)
          reinterpret_cast<bf16*>(Cout)[(size_t)row * N + col] = (bf16)v;
        else
          reinterpret_cast<float*>(Cout)[(size_t)row * N + col] = v;
      }
    }
  }
}

// ---------------- Flash attention ----------------
// grid: (S/128, B*H). block 256 = 4 waves; wave handles 32 q rows. KV chunks of 64.
__global__ __launch_bounds__(256)
void attn_kernel(const bf16* __restrict__ Q, const bf16* __restrict__ K,
                 const bf16* __restrict__ V, bf16* __restrict__ CTX) {
  const int bh = blockIdx.y;
  const int h = bh & (H_ - 1), b = bh >> 4;
  const int q0 = blockIdx.x * 128;
  const int tid = threadIdx.x, wave = tid >> 6, lane = tid & 63;
  const int g = lane >> 4, r16 = lane & 15;
  const bf16* Qb = Q + ((size_t)b * S_) * D_ + h * HD_;
  const bf16* Kb = K + ((size_t)b * S_) * D_ + h * HD_;
  const bf16* Vb = V + ((size_t)b * S_) * D_ + h * HD_;

  __shared__ bf16 Klds[64 * 72];    // [kv][d], stride 72 (pad 8 -> conflict-light)
  __shared__ bf16 Vtlds[64 * 72];   // [d][kv]
  __shared__ bf16 Plds[4][32 * 72]; // per-wave P tile [q][kv]

  // Q fragments in registers (reused all chunks)
  bf16x8 qf[2][2];
#pragma unroll
  for (int mf = 0; mf < 2; ++mf)
#pragma unroll
    for (int ks = 0; ks < 2; ++ks)
      qf[mf][ks] = *reinterpret_cast<const bf16x8*>(
          &Qb[(size_t)(q0 + wave * 32 + mf * 16 + r16) * D_ + ks * 32 + g * 8]);

  f32x4 ctxa[2][4] = {};
  float mrun[2][4], lrun[2][4];
#pragma unroll
  for (int mf = 0; mf < 2; ++mf)
#pragma unroll
    for (int r = 0; r < 4; ++r) { mrun[mf][r] = -1e30f; lrun[mf][r] = 0.f; }

  for (int kv0 = 0; kv0 < S_; kv0 += 64) {
    __syncthreads();
    // stage K chunk [64][64] row-major, coalesced
#pragma unroll
    for (int c = 0; c < 2; ++c) {
      const int row = c * 32 + (tid >> 3);
      const int col = (tid & 7) << 3;
      *reinterpret_cast<bf16x8*>(&Klds[row * 72 + col]) =
          *reinterpret_cast<const bf16x8*>(&Kb[(size_t)(kv0 + row) * D_ + col]);
    }
    // stage V transposed: lane = kv row, wave = d-group; scatter writes conflict-free
#pragma unroll
    for (int c = 0; c < 2; ++c) {
      const int d0 = wave * 16 + c * 8;
      bf16x8 v8 = *reinterpret_cast<const bf16x8*>(&Vb[(size_t)(kv0 + lane) * D_ + d0]);
#pragma unroll
      for (int j = 0; j < 8; ++j)
        Vtlds[(d0 + j) * 72 + lane] = v8[j];
    }
    __syncthreads();

    // QK^T -> sc[mf][nb], rows=q, cols=kv
    f32x4 sc[2][4] = {};
#pragma unroll
    for (int ks = 0; ks < 2; ++ks)
#pragma unroll
      for (int nb = 0; nb < 4; ++nb) {
        bf16x8 kf = *reinterpret_cast<const bf16x8*>(
            &Klds[(nb * 16 + r16) * 72 + ks * 32 + g * 8]);
#pragma unroll
        for (int mf = 0; mf < 2; ++mf)
          sc[mf][nb] = mfma16(qf[mf][ks], kf, sc[mf][nb]);
      }
    // scale 1/sqrt(64)
#pragma unroll
    for (int mf = 0; mf < 2; ++mf)
#pragma unroll
      for (int nb = 0; nb < 4; ++nb)
        sc[mf][nb] *= 0.125f;

    // online softmax per q-row (row = g*4+r within 16-block)
#pragma unroll
    for (int mf = 0; mf < 2; ++mf)
#pragma unroll
      for (int r = 0; r < 4; ++r) {
        float mx = fmaxf(fmaxf(sc[mf][0][r], sc[mf][1][r]),
                         fmaxf(sc[mf][2][r], sc[mf][3][r]));
        mx = fmaxf(mx, __shfl_xor(mx, 1));
        mx = fmaxf(mx, __shfl_xor(mx, 2));
        mx = fmaxf(mx, __shfl_xor(mx, 4));
        mx = fmaxf(mx, __shfl_xor(mx, 8));
        const float mo = mrun[mf][r];
        const float mn = fmaxf(mo, mx);
        const float alpha = __expf(mo - mn);
        mrun[mf][r] = mn;
        float rs = 0.f;
#pragma unroll
        for (int nb = 0; nb < 4; ++nb) {
          const float p = __expf(sc[mf][nb][r] - mn);
          sc[mf][nb][r] = p;
          rs += p;
        }
        rs += __shfl_xor(rs, 1);
        rs += __shfl_xor(rs, 2);
        rs += __shfl_xor(rs, 4);
        rs += __shfl_xor(rs, 8);
        lrun[mf][r] = lrun[mf][r] * alpha + rs;
#pragma unroll
        for (int nd = 0; nd < 4; ++nd) ctxa[mf][nd][r] *= alpha;
      }

    // write P (bf16) to per-wave LDS; within-wave DS ordering suffices
#pragma unroll
    for (int mf = 0; mf < 2; ++mf)
#pragma unroll
      for (int nb = 0; nb < 4; ++nb)
#pragma unroll
        for (int r = 0; r < 4; ++r)
          Plds[wave][(mf * 16 + g * 4 + r) * 72 + nb * 16 + r16] =
              (bf16)sc[mf][nb][r];
    asm volatile("" ::: "memory");

    // PV: ctx[q][d] += P[q][kv] * V[kv][d]
#pragma unroll
    for (int ks = 0; ks < 2; ++ks) {
      bf16x8 pa[2];
#pragma unroll
      for (int mf = 0; mf < 2; ++mf)
        pa[mf] = *reinterpret_cast<const bf16x8*>(
            &Plds[wave][(mf * 16 + r16) * 72 + ks * 32 + g * 8]);
#pragma unroll
      for (int nd = 0; nd < 4; ++nd) {
        bf16x8 vf = *reinterpret_cast<const bf16x8*>(
            &Vtlds[(nd * 16 + r16) * 72 + ks * 32 + g * 8]);
#pragma unroll
        for (int mf = 0; mf < 2; ++mf)
          ctxa[mf][nd] = mfma16(pa[mf], vf, ctxa[mf][nd]);
      }
    }
  }

  // finalize: divide by l, write ctx (bf16) in [B*S, D] layout
#pragma unroll
  for (int mf = 0; mf < 2; ++mf)
#pragma unroll
    for (int r = 0; r < 4; ++r) {
      const float inv = 1.0f / lrun[mf][r];
      const size_t row = (size_t)(b * S_ + q0 + wave * 32 + mf * 16 + g * 4 + r);
#pragma unroll
      for (int nd = 0; nd < 4; ++nd)
        CTX[row * D_ + h * HD_ + nd * 16 + r16] = (bf16)(ctxa[mf][nd][r] * inv);
    }
}

// ---------------- launch ----------------
extern "C" void kernel_launch(void* const* d_in, const int* in_sizes, int n_in,
                              void* d_out, int out_size, void* d_ws, size_t ws_size,
                              hipStream_t stream) {
  const float* x  = (const float*)d_in[0];
  const float* Wq = (const float*)d_in[1]; const float* bq = (const float*)d_in[2];
  const float* Wk = (const float*)d_in[3]; const float* bk = (const float*)d_in[4];
  const float* Wv = (const float*)d_in[5]; const float* bv = (const float*)d_in[6];
  const float* Wo = (const float*)d_in[7]; const float* bo = (const float*)d_in[8];

  char* ws = (char*)d_ws;
  // layout (bytes): xb 16M | wq..wo 4x2M | q 16M | k 16M | v 16M | ctx 16M = 88M total
  bf16* xb  = (bf16*)(ws);
  bf16* wqb = (bf16*)(ws + 16777216);
  bf16* wkb = (bf16*)(ws + 18874368);
  bf16* wvb = (bf16*)(ws + 20971520);
  bf16* wob = (bf16*)(ws + 23068672);
  bf16* qb  = (bf16*)(ws + 25165824);
  bf16* kb  = (bf16*)(ws + 41943040);
  bf16* vb  = (bf16*)(ws + 58720256);
  bf16* ctx = (bf16*)(ws + 75497472);

  cvt_kernel<<<2048, 256, 0, stream>>>(x,  xb,  2097152); // 8M elems / 4
  cvt_kernel<<<512,  256, 0, stream>>>(Wq, wqb, 262144);
  cvt_kernel<<<512,  256, 0, stream>>>(Wk, wkb, 262144);
  cvt_kernel<<<512,  256, 0, stream>>>(Wv, wvb, 262144);
  cvt_kernel<<<512,  256, 0, stream>>>(Wo, wob, 262144);

  dim3 gg(1024 / 128, 8192 / 128); // (8, 64)
  gemm_bt<true><<<gg, 256, 0, stream>>>(xb, wqb, bq, qb, 8192, 1024, 1024);
  gemm_bt<true><<<gg, 256, 0, stream>>>(xb, wkb, bk, kb, 8192, 1024, 1024);
  gemm_bt<true><<<gg, 256, 0, stream>>>(xb, wvb, bv, vb, 8192, 1024, 1024);

  attn_kernel<<<dim3(2048 / 128, B_ * H_), 256, 0, stream>>>(qb, kb, vb, ctx);

  gemm_bt<false><<<gg, 256, 0, stream>>>(ctx, wob, bo, d_out, 8192, 1024, 1024);
}

// Round 2
// 294.398 us; speedup vs baseline: 1.4524x; 1.4524x over previous
//
#include <hip/hip_runtime.h>
#include <hip/hip_bf16.h>

// MHA: B=4, S=2048, D=1024, H=16, HD=64. fp32 in/out, bf16 MFMA internally.
typedef __bf16 bf16;
typedef __bf16 bf16x8 __attribute__((ext_vector_type(8)));
typedef __bf16 bf16x4 __attribute__((ext_vector_type(4)));
typedef float f32x4 __attribute__((ext_vector_type(4)));

#define B_ 4
#define S_ 2048
#define D_ 1024
#define H_ 16
#define HD_ 64
#define LOG2E 1.4426950408889634f

static __device__ __forceinline__ f32x4 mfma16(bf16x8 a, bf16x8 b, f32x4 c) {
  return __builtin_amdgcn_mfma_f32_16x16x32_bf16(a, b, c, 0, 0, 0);
}

static __device__ __forceinline__ void gload_lds16(const void* g, void* l) {
  __builtin_amdgcn_global_load_lds(
      (const __attribute__((address_space(1))) void*)g,
      (__attribute__((address_space(3))) void*)l, 16, 0, 0);
}

// ---------------- fp32 -> bf16 conversion ----------------
__global__ void cvt_kernel(const float* __restrict__ in, bf16* __restrict__ out, int n4) {
  int i = blockIdx.x * blockDim.x + threadIdx.x;
  const int stride = gridDim.x * blockDim.x;
  for (; i < n4; i += stride) {
    float4 v = reinterpret_cast<const float4*>(in)[i];
    bf16x4 o;
    o[0] = (bf16)v.x; o[1] = (bf16)v.y; o[2] = (bf16)v.z; o[3] = (bf16)v.w;
    reinterpret_cast<bf16x4*>(out)[i] = o;
  }
}

// ---------------- GEMM: C[m][n] = (sum_k A[m][k]*W[n][k] + bias[.]) * scale --------
// 128x128 tile, BK=32, 4 waves (2x2), each wave 64x64 output.
template<bool OUT_BF16, bool BIAS_ROW>
__global__ __launch_bounds__(256)
void gemm_bt(const bf16* __restrict__ A, const bf16* __restrict__ W,
             const float* __restrict__ bias, void* __restrict__ Cout,
             int M, int N, int K, float scale) {
  __shared__ bf16 Alds[128 * 32];
  __shared__ bf16 Blds[128 * 32];
  const int tid = threadIdx.x;
  const int wave = tid >> 6, lane = tid & 63;
  const int g = lane >> 4, r16 = lane & 15;
  const int m0 = blockIdx.y * 128, n0 = blockIdx.x * 128;
  const int wm = (wave >> 1) * 64, wn = (wave & 1) * 64;

  f32x4 acc[4][4] = {};

  const int srow = (wave << 5) + (lane >> 2);
  const int scol = (lane & 3) << 3;
  const int nkt = K >> 5;

  for (int kt = 0; kt < nkt; ++kt) {
    __syncthreads();
    const int kb = kt << 5;
    gload_lds16(&A[(size_t)(m0 + srow) * K + kb + scol],      &Alds[(wave << 10)]);
    gload_lds16(&A[(size_t)(m0 + srow + 16) * K + kb + scol], &Alds[(wave << 10) + 512]);
    gload_lds16(&W[(size_t)(n0 + srow) * K + kb + scol],      &Blds[(wave << 10)]);
    gload_lds16(&W[(size_t)(n0 + srow + 16) * K + kb + scol], &Blds[(wave << 10) + 512]);
    __syncthreads();

    bf16x8 af[4], bf_[4];
#pragma unroll
    for (int i = 0; i < 4; ++i) {
      af[i]  = *reinterpret_cast<const bf16x8*>(&Alds[(wm + i * 16 + r16) * 32 + g * 8]);
      bf_[i] = *reinterpret_cast<const bf16x8*>(&Blds[(wn + i * 16 + r16) * 32 + g * 8]);
    }
#pragma unroll
    for (int i = 0; i < 4; ++i)
#pragma unroll
      for (int j = 0; j < 4; ++j)
        acc[i][j] = mfma16(af[i], bf_[j], acc[i][j]);
  }

#pragma unroll
  for (int i = 0; i < 4; ++i) {
#pragma unroll
    for (int j = 0; j < 4; ++j) {
      const int col = n0 + wn + j * 16 + r16;
      float bcol = BIAS_ROW ? 0.f : bias[col];
#pragma unroll
      for (int r = 0; r < 4; ++r) {
        const int row = m0 + wm + i * 16 + g * 4 + r;
        const float bv = BIAS_ROW ? bias[row] : bcol;
        const float v = (acc[i][j][r] + bv) * scale;
        if (OUT_BF16)
          reinterpret_cast<bf16*>(Cout)[(size_t)row * N + col] = (bf16)v;
        else
          reinterpret_cast<float*>(Cout)[(size_t)row * N + col] = v;
      }
    }
  }
}

// ---------------- Flash attention (swapped QK^T, lane-local softmax) -------------
// grid: (S/128, B*H). block 256 = 4 waves; wave handles 32 q rows (2 tiles of 16).
// Q: [B*S][D] bf16, pre-scaled by 0.125*LOG2E. K: [B*S][D] bf16. Vt: [D][B*S] bf16.
// LDS: Klds [64kv][64d] swz | Vtlds [64d][64kv] swz | Plds per-wave [2mf][16q][64kv] swz
__global__ __launch_bounds__(256)
void attn_kernel(const bf16* __restrict__ Q, const bf16* __restrict__ K,
                 const bf16* __restrict__ Vt, bf16* __restrict__ CTX) {
  const int bh = blockIdx.y;
  const int h = bh & (H_ - 1), b = bh >> 4;
  const int q0 = blockIdx.x * 128;
  const int tid = threadIdx.x, wave = tid >> 6, lane = tid & 63;
  const int g = lane >> 4, r16 = lane & 15;
  const int sw = (r16 & 7) << 4;  // XOR swizzle for my frag rows

  const bf16* Qb  = Q + ((size_t)b * S_) * D_ + h * HD_;
  const bf16* Kb  = K + ((size_t)b * S_) * D_ + h * HD_;
  const bf16* Vtb = Vt + (size_t)(h * HD_) * (B_ * S_) + b * S_;

  __shared__ __align__(16) char lds[32768];
  char* Klds  = lds;           // 8 KB
  char* Vtlds = lds + 8192;    // 8 KB
  char* Plds  = lds + 16384;   // 16 KB: wave*4096 + mf*2048 + row*128 + swz(col)

  // Q fragments (B-operand): qf[mf][ks][j] = Q[q=r16][d=ks*32+g*8+j]
  bf16x8 qf[2][2];
#pragma unroll
  for (int mf = 0; mf < 2; ++mf)
#pragma unroll
    for (int ks = 0; ks < 2; ++ks)
      qf[mf][ks] = *reinterpret_cast<const bf16x8*>(
          &Qb[(size_t)(q0 + wave * 32 + mf * 16 + r16) * D_ + ks * 32 + g * 8]);

  f32x4 ctxa[4][2] = {};          // [nd d-tile][mf], C[d][q]: q=r16, d=nd*16+g*4+reg
  float mrun[2] = {-1e30f, -1e30f};
  float lrun[2] = {0.f, 0.f};

  // staging map: slot s (0..511): row=s>>3, colslot=s&7 (16B units)
  const int srow0 = tid >> 3, scs0 = (tid & 7) << 4;
  const int srow1 = (tid + 256) >> 3, scs1 = scs0;

  for (int kv0 = 0; kv0 < S_; kv0 += 64) {
    // prefetch globals (no LDS hazard before barrier)
    bf16x8 kst0 = *reinterpret_cast<const bf16x8*>(&Kb[(size_t)(kv0 + srow0) * D_ + (scs0 >> 1)]);
    bf16x8 kst1 = *reinterpret_cast<const bf16x8*>(&Kb[(size_t)(kv0 + srow1) * D_ + (scs1 >> 1)]);
    bf16x8 vst0 = *reinterpret_cast<const bf16x8*>(&Vtb[(size_t)srow0 * (B_ * S_) + kv0 + (scs0 >> 1)]);
    bf16x8 vst1 = *reinterpret_cast<const bf16x8*>(&Vtb[(size_t)srow1 * (B_ * S_) + kv0 + (scs1 >> 1)]);
    __syncthreads();  // previous chunk's frag reads complete
    *reinterpret_cast<bf16x8*>(Klds  + srow0 * 128 + (scs0 ^ ((srow0 & 7) << 4))) = kst0;
    *reinterpret_cast<bf16x8*>(Klds  + srow1 * 128 + (scs1 ^ ((srow1 & 7) << 4))) = kst1;
    *reinterpret_cast<bf16x8*>(Vtlds + srow0 * 128 + (scs0 ^ ((srow0 & 7) << 4))) = vst0;
    *reinterpret_cast<bf16x8*>(Vtlds + srow1 * 128 + (scs1 ^ ((srow1 & 7) << 4))) = vst1;
    __syncthreads();  // staged

    // QK^T (swapped): sc[t][mf] = S[kv=t*16+g*4+reg][q=r16]
    f32x4 sc[4][2] = {};
#pragma unroll
    for (int ks = 0; ks < 2; ++ks) {
      const int co = (ks * 64 + g * 16) ^ sw;
#pragma unroll
      for (int t = 0; t < 4; ++t) {
        bf16x8 kf = *reinterpret_cast<const bf16x8*>(Klds + (t * 16 + r16) * 128 + co);
        sc[t][0] = mfma16(kf, qf[0][ks], sc[t][0]);
        sc[t][1] = mfma16(kf, qf[1][ks], sc[t][1]);
      }
    }

    // lane-local softmax (scores already in log2 domain)
#pragma unroll
    for (int mf = 0; mf < 2; ++mf) {
      float mx = sc[0][mf][0];
#pragma unroll
      for (int t = 0; t < 4; ++t)
#pragma unroll
        for (int r = 0; r < 4; ++r) mx = fmaxf(mx, sc[t][mf][r]);
      mx = fmaxf(mx, __shfl_xor(mx, 16));
      mx = fmaxf(mx, __shfl_xor(mx, 32));
      float mo = mrun[mf];
      if (!__all(mx <= mo + 8.f)) {  // defer-max: rescale only on big growth
        const float mn = fmaxf(mo, mx);
        const float al = exp2f(mo - mn);
        lrun[mf] *= al;
#pragma unroll
        for (int nd = 0; nd < 4; ++nd) ctxa[nd][mf] *= al;
        mrun[mf] = mn;
        mo = mn;
      }
      float rs = 0.f;
#pragma unroll
      for (int t = 0; t < 4; ++t)
#pragma unroll
        for (int r = 0; r < 4; ++r) {
          const float p = exp2f(sc[t][mf][r] - mo);
          sc[t][mf][r] = p;
          rs += p;
        }
      rs += __shfl_xor(rs, 16);
      rs += __shfl_xor(rs, 32);
      lrun[mf] += rs;
      // pack P^T[q=r16][kv] into per-wave LDS (b64 writes, swizzled)
#pragma unroll
      for (int t = 0; t < 4; ++t) {
        bf16x4 pv;
        pv[0] = (bf16)sc[t][mf][0]; pv[1] = (bf16)sc[t][mf][1];
        pv[2] = (bf16)sc[t][mf][2]; pv[3] = (bf16)sc[t][mf][3];
        *reinterpret_cast<bf16x4*>(Plds + wave * 4096 + mf * 2048 + r16 * 128 +
                                   ((t * 32 + g * 8) ^ sw)) = pv;
      }
    }
    asm volatile("" ::: "memory");

    // PV: ctx[d][q] += Vt[d][kv] * P[kv][q]
#pragma unroll
    for (int ks = 0; ks < 2; ++ks) {
      const int co = (ks * 64 + g * 16) ^ sw;
      bf16x8 pf0 = *reinterpret_cast<const bf16x8*>(Plds + wave * 4096 + r16 * 128 + co);
      bf16x8 pf1 = *reinterpret_cast<const bf16x8*>(Plds + wave * 4096 + 2048 + r16 * 128 + co);
#pragma unroll
      for (int nd = 0; nd < 4; ++nd) {
        bf16x8 vf = *reinterpret_cast<const bf16x8*>(Vtlds + (nd * 16 + r16) * 128 + co);
        ctxa[nd][0] = mfma16(vf, pf0, ctxa[nd][0]);
        ctxa[nd][1] = mfma16(vf, pf1, ctxa[nd][1]);
      }
    }
  }

  // epilogue: normalize, transpose ctx^T[d][q] -> [q][d] via per-wave LDS, store
  __syncthreads();  // all waves done with K/Vt/P buffers
  char* Cw = Plds + wave * 4096;  // reuse: [32 q][64 d] rows of 128B, swizzled
#pragma unroll
  for (int mf = 0; mf < 2; ++mf) {
    const float inv = 1.0f / lrun[mf];
#pragma unroll
    for (int nd = 0; nd < 4; ++nd) {
      bf16x4 cv;
#pragma unroll
      for (int r = 0; r < 4; ++r) cv[r] = (bf16)(ctxa[nd][mf][r] * inv);
      *reinterpret_cast<bf16x4*>(Cw + (mf * 16 + r16) * 128 + ((nd * 32 + g * 8) ^ sw)) = cv;
    }
  }
  asm volatile("" ::: "memory");
#pragma unroll
  for (int i = 0; i < 4; ++i) {
    const int s = i * 64 + lane;
    const int row = s >> 3, cs = (s & 7) << 4;
    bf16x8 v = *reinterpret_cast<const bf16x8*>(Cw + row * 128 + (cs ^ ((row & 7) << 4)));
    *reinterpret_cast<bf16x8*>(
        &CTX[(size_t)(b * S_ + q0 + wave * 32 + row) * D_ + h * HD_ + (cs >> 1)]) = v;
  }
}

// ---------------- launch ----------------
extern "C" void kernel_launch(void* const* d_in, const int* in_sizes, int n_in,
                              void* d_out, int out_size, void* d_ws, size_t ws_size,
                              hipStream_t stream) {
  const float* x  = (const float*)d_in[0];
  const float* Wq = (const float*)d_in[1]; const float* bq = (const float*)d_in[2];
  const float* Wk = (const float*)d_in[3]; const float* bk = (const float*)d_in[4];
  const float* Wv = (const float*)d_in[5]; const float* bv = (const float*)d_in[6];
  const float* Wo = (const float*)d_in[7]; const float* bo = (const float*)d_in[8];

  char* ws = (char*)d_ws;
  const size_t MB = 1048576;
  bf16* xb  = (bf16*)(ws);            // 16MB
  bf16* wqb = (bf16*)(ws + 16 * MB);  // 2MB
  bf16* wkb = (bf16*)(ws + 18 * MB);
  bf16* wvb = (bf16*)(ws + 20 * MB);
  bf16* wob = (bf16*)(ws + 22 * MB);
  bf16* qb  = (bf16*)(ws + 24 * MB);  // 16MB
  bf16* kb  = (bf16*)(ws + 40 * MB);  // 16MB
  bf16* vtb = (bf16*)(ws + 56 * MB);  // 16MB, [1024 d][8192 tok]
  bf16* ctx = (bf16*)(ws + 72 * MB);  // 16MB

  cvt_kernel<<<2048, 256, 0, stream>>>(x,  xb,  2097152);
  cvt_kernel<<<512,  256, 0, stream>>>(Wq, wqb, 262144);
  cvt_kernel<<<512,  256, 0, stream>>>(Wk, wkb, 262144);
  cvt_kernel<<<512,  256, 0, stream>>>(Wv, wvb, 262144);
  cvt_kernel<<<512,  256, 0, stream>>>(Wo, wob, 262144);

  dim3 gg(1024 / 128, 8192 / 128); // (8, 64)
  // Q pre-scaled by 0.125*log2(e) so attention softmax runs in exp2 domain
  gemm_bt<true,  false><<<gg, 256, 0, stream>>>(xb, wqb, bq, qb, 8192, 1024, 1024, 0.125f * LOG2E);
  gemm_bt<true,  false><<<gg, 256, 0, stream>>>(xb, wkb, bk, kb, 8192, 1024, 1024, 1.0f);
  // V transposed: Vt[d][token] = Wv[d,:]·x[tok,:] + bv[d]  (A/W roles swapped)
  dim3 gv(8192 / 128, 1024 / 128); // (64, 8)
  gemm_bt<true,  true ><<<gv, 256, 0, stream>>>(wvb, xb, bv, vtb, 1024, 8192, 1024, 1.0f);

  attn_kernel<<<dim3(2048 / 128, B_ * H_), 256, 0, stream>>>(qb, kb, vtb, ctx);

  gemm_bt<false, false><<<gg, 256, 0, stream>>>(ctx, wob, bo, d_out, 8192, 1024, 1024, 1.0f);
}

// Round 4
// 246.372 us; speedup vs baseline: 1.7355x; 1.1949x over previous
//
#include <hip/hip_runtime.h>
#include <hip/hip_bf16.h>

// MHA: B=4, S=2048, D=1024, H=16, HD=64. fp32 in/out, bf16 MFMA internally.
typedef __bf16 bf16;
typedef __bf16 bf16x8 __attribute__((ext_vector_type(8)));
typedef __bf16 bf16x4 __attribute__((ext_vector_type(4)));
typedef float f32x4 __attribute__((ext_vector_type(4)));
typedef float f32x16 __attribute__((ext_vector_type(16)));
typedef unsigned int u32;
typedef u32 u32x4 __attribute__((ext_vector_type(4)));

#define B_ 4
#define S_ 2048
#define D_ 1024
#define H_ 16
#define HD_ 64
#define LOG2E 1.4426950408889634f

static __device__ __forceinline__ f32x4 mfma16(bf16x8 a, bf16x8 b, f32x4 c) {
  return __builtin_amdgcn_mfma_f32_16x16x32_bf16(a, b, c, 0, 0, 0);
}
static __device__ __forceinline__ f32x16 mfma32(bf16x8 a, bf16x8 b, f32x16 c) {
  return __builtin_amdgcn_mfma_f32_32x32x16_bf16(a, b, c, 0, 0, 0);
}
static __device__ __forceinline__ void gload_lds16(const void* g, void* l) {
  __builtin_amdgcn_global_load_lds(
      (const __attribute__((address_space(1))) void*)g,
      (__attribute__((address_space(3))) void*)l, 16, 0, 0);
}
static __device__ __forceinline__ u32 pack2(float lo, float hi) {
  union { bf16 h[2]; u32 u; } un;
  un.h[0] = (bf16)lo; un.h[1] = (bf16)hi;
  return un.u;
}

// ---------------- fp32 -> bf16 conversion ----------------
__global__ void cvt_kernel(const float* __restrict__ in, bf16* __restrict__ out, int n4) {
  int i = blockIdx.x * blockDim.x + threadIdx.x;
  const int stride = gridDim.x * blockDim.x;
  for (; i < n4; i += stride) {
    float4 v = reinterpret_cast<const float4*>(in)[i];
    bf16x4 o;
    o[0] = (bf16)v.x; o[1] = (bf16)v.y; o[2] = (bf16)v.z; o[3] = (bf16)v.w;
    reinterpret_cast<bf16x4*>(out)[i] = o;
  }
}
// 4 weight matrices in one launch (blockIdx.y selects)
__global__ void cvtw_kernel(const float* __restrict__ w0, const float* __restrict__ w1,
                            const float* __restrict__ w2, const float* __restrict__ w3,
                            bf16* __restrict__ o0, bf16* __restrict__ o1,
                            bf16* __restrict__ o2, bf16* __restrict__ o3, int n4) {
  const float* in = blockIdx.y == 0 ? w0 : blockIdx.y == 1 ? w1 : blockIdx.y == 2 ? w2 : w3;
  bf16* out = blockIdx.y == 0 ? o0 : blockIdx.y == 1 ? o1 : blockIdx.y == 2 ? o2 : o3;
  const int i = blockIdx.x * blockDim.x + threadIdx.x;
  float4 v = reinterpret_cast<const float4*>(in)[i];
  bf16x4 o;
  o[0] = (bf16)v.x; o[1] = (bf16)v.y; o[2] = (bf16)v.z; o[3] = (bf16)v.w;
  reinterpret_cast<bf16x4*>(out)[i] = o;
}

// ---------------- GEMM: C[m][n] = (sum_k A[m][k]*W[n][k] + bias[.]) * scale --------
// 128x128 tile, BK=32, 4 waves (2x2), each wave 64x64 output. XCD-swizzled grid.
template<bool OUT_BF16, bool BIAS_ROW>
__global__ __launch_bounds__(256)
void gemm_bt(const bf16* __restrict__ A, const bf16* __restrict__ W,
             const float* __restrict__ bias, void* __restrict__ Cout,
             int M, int N, int K, float scale) {
  __shared__ bf16 Alds[128 * 32];
  __shared__ bf16 Blds[128 * 32];
  const int tid = threadIdx.x;
  const int wave = tid >> 6, lane = tid & 63;
  const int g = lane >> 4, r16 = lane & 15;
  // bijective XCD swizzle (nwg % 8 == 0): each XCD gets a contiguous run
  const unsigned nwgx = gridDim.x;
  const unsigned nwg = nwgx * gridDim.y;
  unsigned lid = blockIdx.x + nwgx * blockIdx.y;
  unsigned swz = (lid & 7) * (nwg >> 3) + (lid >> 3);
  const int m0 = (int)(swz / nwgx) * 128, n0 = (int)(swz % nwgx) * 128;
  const int wm = (wave >> 1) * 64, wn = (wave & 1) * 64;

  f32x4 acc[4][4] = {};

  const int srow = (wave << 5) + (lane >> 2);
  const int scol = (lane & 3) << 3;
  const int nkt = K >> 5;

  for (int kt = 0; kt < nkt; ++kt) {
    __syncthreads();
    const int kb = kt << 5;
    gload_lds16(&A[(size_t)(m0 + srow) * K + kb + scol],      &Alds[(wave << 10)]);
    gload_lds16(&A[(size_t)(m0 + srow + 16) * K + kb + scol], &Alds[(wave << 10) + 512]);
    gload_lds16(&W[(size_t)(n0 + srow) * K + kb + scol],      &Blds[(wave << 10)]);
    gload_lds16(&W[(size_t)(n0 + srow + 16) * K + kb + scol], &Blds[(wave << 10) + 512]);
    __syncthreads();

    bf16x8 af[4], bf_[4];
#pragma unroll
    for (int i = 0; i < 4; ++i) {
      af[i]  = *reinterpret_cast<const bf16x8*>(&Alds[(wm + i * 16 + r16) * 32 + g * 8]);
      bf_[i] = *reinterpret_cast<const bf16x8*>(&Blds[(wn + i * 16 + r16) * 32 + g * 8]);
    }
#pragma unroll
    for (int i = 0; i < 4; ++i)
#pragma unroll
      for (int j = 0; j < 4; ++j)
        acc[i][j] = mfma16(af[i], bf_[j], acc[i][j]);
  }

#pragma unroll
  for (int i = 0; i < 4; ++i) {
#pragma unroll
    for (int j = 0; j < 4; ++j) {
      const int col = n0 + wn + j * 16 + r16;
      float bcol = BIAS_ROW ? 0.f : bias[col];
#pragma unroll
      for (int r = 0; r < 4; ++r) {
        const int row = m0 + wm + i * 16 + g * 4 + r;
        const float bv = BIAS_ROW ? bias[row] : bcol;
        const float v = (acc[i][j][r] + bv) * scale;
        if (OUT_BF16)
          reinterpret_cast<bf16*>(Cout)[(size_t)row * N + col] = (bf16)v;
        else
          reinterpret_cast<float*>(Cout)[(size_t)row * N + col] = v;
      }
    }
  }
}

// ---------------- Flash attention: 32x32 MFMA, in-register P via shfl_xor(32) ------
// grid (S/128, B*H), block 256 = 4 waves, wave owns 32 q rows (q = q0+wave*32+l32).
// KV chunk 64 = 2 kv-tiles; K/V double-buffered in LDS (16KB per buf), 1 barrier/chunk.
// Q pre-scaled by 0.125*log2(e): softmax in exp2 domain.
// Layouts (32x32x16): A: row=l&31, k=8*(l>>5)+j. B: col=l&31, k=8*(l>>5)+j.
//                     C/D: col=l&31, row=(reg&3)+8*(reg>>2)+4*(l>>5).
__global__ __launch_bounds__(256)
void attn_kernel(const bf16* __restrict__ Q, const bf16* __restrict__ K,
                 const bf16* __restrict__ Vt, bf16* __restrict__ CTX) {
  const int bh = blockIdx.y;
  const int h = bh & (H_ - 1), b = bh >> 4;
  const int q0 = blockIdx.x * 128;
  const int tid = threadIdx.x, wave = tid >> 6, lane = tid & 63;
  const int l32 = lane & 31, hi = lane >> 5;

  const bf16* Qb  = Q  + ((size_t)b * S_) * D_ + h * HD_;
  const bf16* Kb  = K  + ((size_t)b * S_) * D_ + h * HD_;
  const bf16* Vtb = Vt + (size_t)(h * HD_) * (B_ * S_) + b * S_;

  __shared__ __align__(16) char lds[32768];  // buf p at p*16384: K[64][128B] + Vt[64][128B]

  // Q B-frags: qf[ks][j] = Q[q][d=16ks+8hi+j]
  const int q = q0 + wave * 32 + l32;
  bf16x8 qf[4];
#pragma unroll
  for (int ks = 0; ks < 4; ++ks)
    qf[ks] = *reinterpret_cast<const bf16x8*>(&Qb[(size_t)q * D_ + ks * 16 + hi * 8]);

  f32x16 ctx0 = {}, ctx1 = {};  // ctx[q(reg-dim)][d = nd*32+l32]
  float mrun = -1e30f, lrun = 0.f;

  // staging: 256 threads cover 64 rows x 8 slots (16B) twice (K and Vt)
  const int srow = tid >> 2;
  const int ss0 = (tid & 3), ss1 = (tid & 3) + 4;
  const int swr = (srow & 7) << 4;
  const int lw0 = srow * 128 + ((ss0 * 16) ^ swr);
  const int lw1 = srow * 128 + ((ss1 * 16) ^ swr);
  const size_t vgo = (size_t)srow * (B_ * S_);
  const int swl = (l32 & 7) << 4;

  auto compute = [&](const char* bK, const char* bV) {
    // QK^T (swapped): sc_t = S^T[kv=32t+rowpat][q=l32]
    f32x16 sc0 = {}, sc1 = {};
    __builtin_amdgcn_s_setprio(1);
#pragma unroll
    for (int ks = 0; ks < 4; ++ks) {
      const int co = (ks * 32 + hi * 16) ^ swl;
      bf16x8 kf0 = *reinterpret_cast<const bf16x8*>(bK + l32 * 128 + co);
      bf16x8 kf1 = *reinterpret_cast<const bf16x8*>(bK + (32 + l32) * 128 + co);
      sc0 = mfma32(kf0, qf[ks], sc0);
      sc1 = mfma32(kf1, qf[ks], sc1);
    }
    __builtin_amdgcn_s_setprio(0);
    // lane-local softmax (one q per lane; halves share q via xor-32)
    float tr[8];
#pragma unroll
    for (int r = 0; r < 8; ++r)
      tr[r] = fmaxf(fmaxf(sc0[2 * r], sc0[2 * r + 1]), fmaxf(sc1[2 * r], sc1[2 * r + 1]));
#pragma unroll
    for (int r = 0; r < 4; ++r) tr[r] = fmaxf(tr[r], tr[r + 4]);
    float mx = fmaxf(fmaxf(tr[0], tr[1]), fmaxf(tr[2], tr[3]));
    mx = fmaxf(mx, __shfl_xor(mx, 32));
    if (!__all(mx <= mrun + 8.f)) {  // defer-max (THR=8, log2 domain)
      const float mn = fmaxf(mrun, mx);
      const float al = __builtin_amdgcn_exp2f(mrun - mn);
      lrun *= al;
#pragma unroll
      for (int r = 0; r < 16; ++r) { ctx0[r] *= al; ctx1[r] *= al; }
      mrun = mn;
    }
    float p0[16], p1[16], rs = 0.f;
#pragma unroll
    for (int r = 0; r < 16; ++r) { p0[r] = __builtin_amdgcn_exp2f(sc0[r] - mrun); rs += p0[r]; }
#pragma unroll
    for (int r = 0; r < 16; ++r) { p1[r] = __builtin_amdgcn_exp2f(sc1[r] - mrun); rs += p1[r]; }
    rs += __shfl_xor(rs, 32);
    lrun += rs;
    // pack P to bf16 words: w[2a+c] = {kv = 8a+4hi+2c, +1} for this lane's q=l32
    u32 w0[8], w1[8];
#pragma unroll
    for (int a = 0; a < 4; ++a)
#pragma unroll
      for (int c = 0; c < 2; ++c) {
        w0[a * 2 + c] = pack2(p0[4 * a + 2 * c], p0[4 * a + 2 * c + 1]);
        w1[a * 2 + c] = pack2(p1[4 * a + 2 * c], p1[4 * a + 2 * c + 1]);
      }
    // PV: 4 kslices of 16 kv. A-frag word j-pair mapping (k = 8hi+j, kv = 16ksp+k):
    //   fw[c]   needs kv {16k1+8hi+2c}   : hi=0 -> own w[4k1+c];  hi=1 -> partner w[4k1+2+c]
    //   fw[2+c] needs kv {16k1+8hi+4+2c} : hi=0 -> partner w[4k1+c]; hi=1 -> own w[4k1+2+c]
    // Cross-half exchange via shfl_xor(32) (unambiguous semantics).
#pragma unroll
    for (int ksp = 0; ksp < 4; ++ksp) {
      const int k1 = ksp & 1;
      const u32* w = (ksp >> 1) ? w1 : w0;
      u32x4 fw;
#pragma unroll
      for (int c = 0; c < 2; ++c) {
        const u32 wa = w[4 * k1 + c];
        const u32 wb = w[4 * k1 + 2 + c];
        const u32 got = (u32)__shfl_xor((int)(hi ? wa : wb), 32);
        fw[c]     = hi ? got : wa;
        fw[2 + c] = hi ? wb : got;
      }
      const bf16x8 pa = __builtin_bit_cast(bf16x8, fw);
      const int co = (ksp * 32 + hi * 16) ^ swl;
      bf16x8 vf0 = *reinterpret_cast<const bf16x8*>(bV + l32 * 128 + co);
      bf16x8 vf1 = *reinterpret_cast<const bf16x8*>(bV + (32 + l32) * 128 + co);
      __builtin_amdgcn_s_setprio(1);
      ctx0 = mfma32(pa, vf0, ctx0);
      ctx1 = mfma32(pa, vf1, ctx1);
      __builtin_amdgcn_s_setprio(0);
    }
  };

  // prologue: stage chunk 0 into buf0
  {
    bf16x8 k0 = *reinterpret_cast<const bf16x8*>(&Kb[(size_t)srow * D_ + ss0 * 8]);
    bf16x8 k1 = *reinterpret_cast<const bf16x8*>(&Kb[(size_t)srow * D_ + ss1 * 8]);
    bf16x8 v0 = *reinterpret_cast<const bf16x8*>(&Vtb[vgo + ss0 * 8]);
    bf16x8 v1 = *reinterpret_cast<const bf16x8*>(&Vtb[vgo + ss1 * 8]);
    *reinterpret_cast<bf16x8*>(lds + lw0) = k0;
    *reinterpret_cast<bf16x8*>(lds + lw1) = k1;
    *reinterpret_cast<bf16x8*>(lds + 8192 + lw0) = v0;
    *reinterpret_cast<bf16x8*>(lds + 8192 + lw1) = v1;
  }
  __syncthreads();

  for (int t = 0; t < 31; ++t) {
    const int kv1 = (t + 1) * 64;
    // issue next-chunk loads early (latency hides under compute)
    bf16x8 k0 = *reinterpret_cast<const bf16x8*>(&Kb[(size_t)(kv1 + srow) * D_ + ss0 * 8]);
    bf16x8 k1 = *reinterpret_cast<const bf16x8*>(&Kb[(size_t)(kv1 + srow) * D_ + ss1 * 8]);
    bf16x8 v0 = *reinterpret_cast<const bf16x8*>(&Vtb[vgo + kv1 + ss0 * 8]);
    bf16x8 v1 = *reinterpret_cast<const bf16x8*>(&Vtb[vgo + kv1 + ss1 * 8]);
    const char* base = lds + (t & 1) * 16384;
    compute(base, base + 8192);
    char* dst = lds + ((t + 1) & 1) * 16384;
    *reinterpret_cast<bf16x8*>(dst + lw0) = k0;
    *reinterpret_cast<bf16x8*>(dst + lw1) = k1;
    *reinterpret_cast<bf16x8*>(dst + 8192 + lw0) = v0;
    *reinterpret_cast<bf16x8*>(dst + 8192 + lw1) = v1;
    __syncthreads();
  }
  compute(lds + 16384, lds + 16384 + 8192);  // chunk 31 from buf1

  // epilogue: normalize + transpose via per-wave LDS (reuse buf0), store
  __syncthreads();
  char* Cw = lds + wave * 4096;  // [32 q][64 d] rows of 128B, swizzled
#pragma unroll
  for (int rg = 0; rg < 16; ++rg) {
    const int ql = (rg & 3) + 8 * (rg >> 2) + 4 * hi;  // q within wave's 32
    const float inv = 1.0f / __shfl(lrun, ql);
    const int swq = (ql & 7) << 4;
    *reinterpret_cast<bf16*>(Cw + ql * 128 + ((l32 * 2) ^ swq)) = (bf16)(ctx0[rg] * inv);
    *reinterpret_cast<bf16*>(Cw + ql * 128 + ((64 + l32 * 2) ^ swq)) = (bf16)(ctx1[rg] * inv);
  }
  asm volatile("" ::: "memory");
#pragma unroll
  for (int i = 0; i < 4; ++i) {
    const int s = i * 64 + lane;
    const int row = s >> 3, cs = (s & 7) * 16;
    bf16x8 v = *reinterpret_cast<const bf16x8*>(Cw + row * 128 + (cs ^ ((row & 7) << 4)));
    *reinterpret_cast<bf16x8*>(
        &CTX[(size_t)(b * S_ + q0 + wave * 32 + row) * D_ + h * HD_ + cs / 2]) = v;
  }
}

// ---------------- launch ----------------
extern "C" void kernel_launch(void* const* d_in, const int* in_sizes, int n_in,
                              void* d_out, int out_size, void* d_ws, size_t ws_size,
                              hipStream_t stream) {
  const float* x  = (const float*)d_in[0];
  const float* Wq = (const float*)d_in[1]; const float* bq = (const float*)d_in[2];
  const float* Wk = (const float*)d_in[3]; const float* bk = (const float*)d_in[4];
  const float* Wv = (const float*)d_in[5]; const float* bv = (const float*)d_in[6];
  const float* Wo = (const float*)d_in[7]; const float* bo = (const float*)d_in[8];

  char* ws = (char*)d_ws;
  const size_t MB = 1048576;
  bf16* xb  = (bf16*)(ws);            // 16MB
  bf16* wqb = (bf16*)(ws + 16 * MB);  // 2MB
  bf16* wkb = (bf16*)(ws + 18 * MB);
  bf16* wvb = (bf16*)(ws + 20 * MB);
  bf16* wob = (bf16*)(ws + 22 * MB);
  bf16* qb  = (bf16*)(ws + 24 * MB);  // 16MB
  bf16* kb  = (bf16*)(ws + 40 * MB);  // 16MB
  bf16* vtb = (bf16*)(ws + 56 * MB);  // 16MB, [1024 d][8192 tok]
  bf16* ctx = (bf16*)(ws + 72 * MB);  // 16MB

  cvt_kernel<<<2048, 256, 0, stream>>>(x, xb, 2097152);
  cvtw_kernel<<<dim3(1024, 4), 256, 0, stream>>>(Wq, Wk, Wv, Wo, wqb, wkb, wvb, wob, 262144);

  dim3 gg(1024 / 128, 8192 / 128); // (8, 64)
  // Q pre-scaled by 0.125*log2(e) so attention softmax runs in exp2 domain
  gemm_bt<true,  false><<<gg, 256, 0, stream>>>(xb, wqb, bq, qb, 8192, 1024, 1024, 0.125f * LOG2E);
  gemm_bt<true,  false><<<gg, 256, 0, stream>>>(xb, wkb, bk, kb, 8192, 1024, 1024, 1.0f);
  // V transposed: Vt[d][token] = Wv[d,:]·x[tok,:] + bv[d]
  dim3 gv(8192 / 128, 1024 / 128); // (64, 8)
  gemm_bt<true,  true ><<<gv, 256, 0, stream>>>(wvb, xb, bv, vtb, 1024, 8192, 1024, 1.0f);

  attn_kernel<<<dim3(2048 / 128, B_ * H_), 256, 0, stream>>>(qb, kb, vtb, ctx);

  gemm_bt<false, false><<<gg, 256, 0, stream>>>(ctx, wob, bo, d_out, 8192, 1024, 1024, 1.0f);
}